// Round 11
// baseline (143.872 us; speedup 1.0000x reference)
//
#include <hip/hip_runtime.h>

// QRNN: SEQ=4096, BATCH=8, CIN=256, HID=256, K=2 (lookback=1)
// R13: R9 (verified best, 138.0us) with gemm K-loop restaged at BK=128:
//      4 stage-steps instead of 8 (barrier/vmcnt-drain count halved), each
//      consumed as TWO BK=64 sub-passes over the same LDS tile (frag regs,
//      MFMA pattern unchanged). LDS 48KB -> 3 blocks/CU = achieved residency.
//      Occupancy lever exhausted (R12 null at 32 waves/CU); dbuf/sync-fold
//      grafts all regressed (R6/R10/R11) -> this targets drain COUNT instead.
//
// ws: zbf 16MB | fbf 16MB | Xbf 16MB (dead after gemm; Ac/Cc/Hs aliased) | Bm 0.5MB

#define SEQn 4096
#define NCH 2048          // BATCH*HID channels
#define CHUNK 32
#define NCHUNK 128

typedef __attribute__((ext_vector_type(8))) short bf16x8;
typedef __attribute__((ext_vector_type(4))) float floatx4;

__device__ __forceinline__ unsigned short f2bf(float x) {
  unsigned int u = __float_as_uint(x);
  u += 0x7fffu + ((u >> 16) & 1u);     // RNE
  return (unsigned short)(u >> 16);
}
__device__ __forceinline__ float bf2f(ushort u) {
  return __uint_as_float((unsigned int)u << 16);
}
__device__ __forceinline__ float sigf(float x) {
  return __builtin_amdgcn_rcpf(1.0f + __expf(-x));
}

// ---- 1) merged pack: blocks [0,1024) pack W, blocks [1024,9218) pack X ----
__global__ void pack_kernel(const float* __restrict__ X,
                            const float* __restrict__ Wz, const float* __restrict__ Wf,
                            ushort* __restrict__ Xbf, ushort* __restrict__ Bm) {
  if (blockIdx.x < 1024) {
    int idx = blockIdx.x * 256 + threadIdx.x;        // 0..262143
    int n = idx >> 9, kin = idx & 511;
    const float* W = (n < 256) ? Wz : Wf;
    int h = n & 255, c = kin & 255, tap = kin >> 8;  // kin<256: tap0 (X[s-1])
    Bm[idx] = f2bf(W[h * 512 + c * 2 + tap]);
  } else {
    int idx = (blockIdx.x - 1024) * 256 + threadIdx.x;
    const int total4 = ((SEQn + 1) * NCH) / 4;       // 2,097,664
    if (idx >= total4) return;
    const int pad4 = NCH / 4;
    float4 v;
    if (idx < pad4) { v.x = 0.f; v.y = 0.f; v.z = 0.f; v.w = 0.f; }
    else v = ((const float4*)X)[idx - pad4];
    ushort4 o;
    o.x = f2bf(v.x); o.y = f2bf(v.y); o.z = f2bf(v.z); o.w = f2bf(v.w);
    ((ushort4*)Xbf)[idx] = o;
  }
}

// ---- 2) GEMM 64x128, BK=128 staged / 2x BK=64 consumed, swizzled LDS ----
// LDS seg (row, s) s in 0..15: holds global k-seg (s&8)|((s&7)^(row&7))
// 1D grid 2048: bn=(id>>3)&3, bm=((id>>5)<<3)|(id&7) -> A-panel sharers same XCD.
__global__ __launch_bounds__(256) void gemm_kernel(
    const ushort* __restrict__ Xbf, const ushort* __restrict__ Bm,
    const float* __restrict__ bz, const float* __restrict__ bfb,
    ushort* __restrict__ zout, ushort* __restrict__ fout) {
  __shared__ __align__(16) char smem_raw[49152];
  ushort* sA = (ushort*)smem_raw;                 // 64 rows x 128 k  (16KB)
  ushort* sB = sA + 8192;                         // 128 cols x 128 k (32KB)
  ushort* sT = (ushort*)smem_raw;                 // epilogue 64 x 136 (17.4KB)

  const int tid  = threadIdx.x;
  const int wave = tid >> 6;
  const int lane = tid & 63;
  const int quad = lane >> 4;
  const int lrow = lane & 15;
  const int wm = wave >> 1;          // 2x2 wave grid, each 32x64 output
  const int wn = wave & 1;
  const int id = blockIdx.x;         // 0..2047
  const int bn = (id >> 3) & 3;      // 0..3 (0,1=Z; 2,3=F)
  const int bm = ((id >> 5) << 3) | (id & 7);   // 0..511

  floatx4 acc[2][4];
#pragma unroll
  for (int i = 0; i < 2; ++i)
#pragma unroll
    for (int j = 0; j < 4; ++j)
      acc[i][j] = (floatx4){0.f, 0.f, 0.f, 0.f};

  // staging coords: A 4 segs/thread (1024 segs), B 8 segs/thread (2048 segs)
  int rowA[4], gkoA[4], rowB[8], gkoB[8];
#pragma unroll
  for (int it = 0; it < 4; ++it) {
    int g = it * 256 + tid;                  // 0..1023
    int row = g >> 4, s = g & 15;
    rowA[it] = row;                          // 0..63
    gkoA[it] = ((((s & 7) ^ (row & 7)) | (s & 8))) * 8;
  }
#pragma unroll
  for (int it = 0; it < 8; ++it) {
    int g = it * 256 + tid;                  // 0..2047
    int row = g >> 4, s = g & 15;
    rowB[it] = row;                          // 0..127
    gkoB[it] = ((((s & 7) ^ (row & 7)) | (s & 8))) * 8;
  }
  char* ldsA = smem_raw + (tid << 4);
  char* ldsB = smem_raw + 16384 + (tid << 4);

  const ushort* Arow = Xbf + (size_t)(bm * 64) * 256;
  const ushort* Brow = Bm + (size_t)(bn * 128) * 512;

  for (int t = 0; t < 4; ++t) {
    const int k0 = t * 128;
    const int addA = (k0 >= 256) ? 1792 : 0;   // tap1 lives +2048-256 (uniform per step)
    __syncthreads();                 // prev iter ds_reads done
#pragma unroll
    for (int it = 0; it < 4; ++it) {
      const int kk = k0 + gkoA[it];
      __builtin_amdgcn_global_load_lds(
          (const __attribute__((address_space(1))) void*)(Arow + (size_t)rowA[it] * 256 + kk + addA),
          (__attribute__((address_space(3))) void*)(ldsA + it * 4096), 16, 0, 0);
    }
#pragma unroll
    for (int it = 0; it < 8; ++it) {
      const int kk = k0 + gkoB[it];
      __builtin_amdgcn_global_load_lds(
          (const __attribute__((address_space(1))) void*)(Brow + (size_t)rowB[it] * 512 + kk),
          (__attribute__((address_space(3))) void*)(ldsB + it * 4096), 16, 0, 0);
    }
    __syncthreads();

    // two BK=64 sub-passes over the staged 128-wide tile
#pragma unroll
    for (int p = 0; p < 2; ++p) {
      bf16x8 af[2][2], bfr[4][2];
#pragma unroll
      for (int fi = 0; fi < 2; ++fi) {
        const int r = wm * 32 + fi * 16 + lrow;
#pragma unroll
        for (int q = 0; q < 2; ++q) {
          const int s = (p * 2 + q) * 4 + quad;          // 0..15
          const int phys = (s & 8) | ((s & 7) ^ (r & 7));
          af[fi][q] = *(const bf16x8*)&sA[r * 128 + phys * 8];
        }
      }
#pragma unroll
      for (int fj = 0; fj < 4; ++fj) {
        const int r = wn * 64 + fj * 16 + lrow;
#pragma unroll
        for (int q = 0; q < 2; ++q) {
          const int s = (p * 2 + q) * 4 + quad;
          const int phys = (s & 8) | ((s & 7) ^ (r & 7));
          bfr[fj][q] = *(const bf16x8*)&sB[r * 128 + phys * 8];
        }
      }
#pragma unroll
      for (int q = 0; q < 2; ++q)
#pragma unroll
        for (int fi = 0; fi < 2; ++fi)
#pragma unroll
          for (int fj = 0; fj < 4; ++fj)
            acc[fi][fj] = __builtin_amdgcn_mfma_f32_16x16x32_bf16(af[fi][q], bfr[fj][q], acc[fi][fj], 0, 0, 0);
    }
  }

  // epilogue: activation -> bf16 -> sT (64 x 136 padded) -> coalesced dwordx4
  const bool isZ = (bn < 2);
  ushort* gout = isZ ? zout : fout;
  const int ncol0 = (bn & 1) * 128;
  const float* bias = isZ ? bz : bfb;
  float bv[4];
#pragma unroll
  for (int fj = 0; fj < 4; ++fj)
    bv[fj] = bias[ncol0 + wn * 64 + fj * 16 + lrow];

  __syncthreads();                   // all ds_reads of sA/sB done (sT aliases)
#pragma unroll
  for (int fi = 0; fi < 2; ++fi)
#pragma unroll
    for (int fj = 0; fj < 4; ++fj)
#pragma unroll
      for (int r = 0; r < 4; ++r) {
        float v = acc[fi][fj][r] + bv[fj];
        float o = isZ ? (v * sigf(1.702f * v)) : sigf(v);
        sT[(wm * 32 + fi * 16 + quad * 4 + r) * 136 + wn * 64 + fj * 16 + lrow] = f2bf(o);
      }
  __syncthreads();
#pragma unroll
  for (int it = 0; it < 4; ++it) {
    int e = tid + it * 256;           // 1024 segs = 64 rows x 16 segs
    int row = e >> 4, seg = e & 15;
    uint4 v = *(uint4*)&sT[row * 136 + seg * 8];
    *(uint4*)(gout + (size_t)(bm * 64 + row) * 256 + ncol0 + seg * 8) = v;
  }
}

// ---- 3) per-chunk reduction, 2 channels/thread ----
__global__ void scanA_kernel(const ushort* __restrict__ z, const ushort* __restrict__ f,
                             float* __restrict__ Ac, float* __restrict__ Cc) {
  int t = blockIdx.x * blockDim.x + threadIdx.x;   // 0..131071
  int ch2 = t & 1023;
  int j = t >> 10;                                  // 0..127
  const size_t base = (size_t)j * CHUNK * NCH + 2 * ch2;
  const ushort* zp = z + base;
  const ushort* fp = f + base;
  float A0 = 1.0f, C0 = 0.0f, A1 = 1.0f, C1 = 0.0f;
#pragma unroll
  for (int i = 0; i < CHUNK; ++i) {
    ushort2 fv = *(const ushort2*)(fp + (size_t)i * NCH);
    ushort2 zv = *(const ushort2*)(zp + (size_t)i * NCH);
    float f0 = bf2f(fv.x), f1 = bf2f(fv.y);
    float a0 = 1.0f - f0, a1 = 1.0f - f1;
    C0 = fmaf(a0, C0, f0 * bf2f(zv.x)); A0 *= a0;
    C1 = fmaf(a1, C1, f1 * bf2f(zv.y)); A1 *= a1;
  }
  float2 Av = {A0, A1}, Cv = {C0, C1};
  *(float2*)(Ac + (size_t)j * NCH + 2 * ch2) = Av;
  *(float2*)(Cc + (size_t)j * NCH + 2 * ch2) = Cv;
}

// ---- 4) cross-chunk scan: one wave per channel, shfl Hillis-Steele ----
__global__ void scanB_kernel(const float* __restrict__ hidden,
                             const float* __restrict__ Ac, const float* __restrict__ Cc,
                             float* __restrict__ Hs) {
  const int lane = threadIdx.x & 63;
  const int ch = blockIdx.x * 4 + (threadIdx.x >> 6);   // 512 blocks x 4 waves
  const int j0 = 2 * lane, j1 = 2 * lane + 1;
  float a0 = Ac[j0 * NCH + ch], c0 = Cc[j0 * NCH + ch];
  float a1 = Ac[j1 * NCH + ch], c1 = Cc[j1 * NCH + ch];
  float a = a0 * a1;
  float c = fmaf(a1, c0, c1);
#pragma unroll
  for (int d = 1; d < 64; d <<= 1) {
    float pa = __shfl_up(a, d, 64);
    float pc = __shfl_up(c, d, 64);
    if (lane >= d) { c = fmaf(a, pc, c); a *= pa; }
  }
  float xa = __shfl_up(a, 1, 64), xc = __shfl_up(c, 1, 64);
  if (lane == 0) { xa = 1.0f; xc = 0.0f; }
  float h0 = hidden[ch];
  float hs0 = fmaf(xa, h0, xc);
  Hs[j0 * NCH + ch] = hs0;
  Hs[j1 * NCH + ch] = fmaf(a0, hs0, c0);
}

// ---- 5) replay within chunk, 2 channels/thread, fp32 out ----
__global__ void scanC_kernel(const ushort* __restrict__ z, const ushort* __restrict__ f,
                             const float* __restrict__ Hs, float* __restrict__ out) {
  int t = blockIdx.x * blockDim.x + threadIdx.x;   // 0..131071
  int ch2 = t & 1023;
  int j = t >> 10;
  float2 hv = *(const float2*)(Hs + (size_t)j * NCH + 2 * ch2);
  float h0 = hv.x, h1 = hv.y;
  const size_t base = (size_t)j * CHUNK * NCH + 2 * ch2;
  const ushort* zp = z + base;
  const ushort* fp = f + base;
  float* op = out + base;
#pragma unroll
  for (int i = 0; i < CHUNK; ++i) {
    ushort2 fv = *(const ushort2*)(fp + (size_t)i * NCH);
    ushort2 zv = *(const ushort2*)(zp + (size_t)i * NCH);
    float f0 = bf2f(fv.x), f1 = bf2f(fv.y);
    h0 = fmaf(f0, bf2f(zv.x) - h0, h0);
    h1 = fmaf(f1, bf2f(zv.y) - h1, h1);
    float2 o = {h0, h1};
    *(float2*)(op + (size_t)i * NCH) = o;
  }
  if (j == NCHUNK - 1) {
    float2 o = {h0, h1};
    *(float2*)(out + (size_t)SEQn * NCH + 2 * ch2) = o;   // h_last row
  }
}

extern "C" void kernel_launch(void* const* d_in, const int* in_sizes, int n_in,
                              void* d_out, int out_size, void* d_ws, size_t ws_size,
                              hipStream_t stream) {
  const float* X      = (const float*)d_in[0];
  const float* hidden = (const float*)d_in[1];
  const float* Wz     = (const float*)d_in[2];
  const float* bz     = (const float*)d_in[3];
  const float* Wf     = (const float*)d_in[4];
  const float* bfb    = (const float*)d_in[5];
  float* out = (float*)d_out;

  char* ws = (char*)d_ws;
  ushort* zbf = (ushort*)ws;                       // 16,777,216 B
  ushort* fbf = (ushort*)(ws + 16777216);          // 16,777,216 B
  ushort* Xbf = (ushort*)(ws + 33554432);          // 16,781,312 B (dead after gemm)
  ushort* Bm  = (ushort*)(ws + 50335744);          //    524,288 B
  // aliased over Xbf (used only after gemm completes):
  float* Ac = (float*)(ws + 33554432);
  float* Cc = (float*)(ws + 34603008);
  float* Hs = (float*)(ws + 35651584);

  pack_kernel<<<9218, 256, 0, stream>>>(X, Wz, Wf, Xbf, Bm);
  gemm_kernel<<<2048, 256, 0, stream>>>(Xbf, Bm, bz, bfb, zbf, fbf);
  scanA_kernel<<<512, 256, 0, stream>>>(zbf, fbf, Ac, Cc);
  scanB_kernel<<<512, 256, 0, stream>>>(hidden, Ac, Cc, Hs);
  scanC_kernel<<<512, 256, 0, stream>>>(zbf, fbf, Hs, out);
}

// Round 12
// 142.751 us; speedup vs baseline: 1.0079x; 1.0079x over previous
//
#include <hip/hip_runtime.h>

// QRNN: SEQ=4096, BATCH=8, CIN=256, HID=256, K=2 (lookback=1)
// R14: R9 (verified best, 138.0us) with scanB DELETED: scanC folds the
//      cross-chunk prefix inline (per-thread serial lookback over L2-resident
//      Ac/Cc, avg 64 iters, chain-independent loads). 4 launches. Gemm schedule
//      frozen at R9 (5 pipelining grafts R6/R10/R11/R12/R13 all null/regressed;
//      only dataflow/geometry changes ever won).
//
// ws: zbf 16MB | fbf 16MB | Xbf 16MB (dead after gemm; Ac/Cc aliased) | Bm 0.5MB

#define SEQn 4096
#define NCH 2048          // BATCH*HID channels
#define CHUNK 32
#define NCHUNK 128

typedef __attribute__((ext_vector_type(8))) short bf16x8;
typedef __attribute__((ext_vector_type(4))) float floatx4;

__device__ __forceinline__ unsigned short f2bf(float x) {
  unsigned int u = __float_as_uint(x);
  u += 0x7fffu + ((u >> 16) & 1u);     // RNE
  return (unsigned short)(u >> 16);
}
__device__ __forceinline__ float bf2f(ushort u) {
  return __uint_as_float((unsigned int)u << 16);
}
__device__ __forceinline__ float sigf(float x) {
  return __builtin_amdgcn_rcpf(1.0f + __expf(-x));
}

// ---- 1) merged pack: blocks [0,1024) pack W, blocks [1024,9218) pack X ----
__global__ void pack_kernel(const float* __restrict__ X,
                            const float* __restrict__ Wz, const float* __restrict__ Wf,
                            ushort* __restrict__ Xbf, ushort* __restrict__ Bm) {
  if (blockIdx.x < 1024) {
    int idx = blockIdx.x * 256 + threadIdx.x;        // 0..262143
    int n = idx >> 9, kin = idx & 511;
    const float* W = (n < 256) ? Wz : Wf;
    int h = n & 255, c = kin & 255, tap = kin >> 8;  // kin<256: tap0 (X[s-1])
    Bm[idx] = f2bf(W[h * 512 + c * 2 + tap]);
  } else {
    int idx = (blockIdx.x - 1024) * 256 + threadIdx.x;
    const int total4 = ((SEQn + 1) * NCH) / 4;       // 2,097,664
    if (idx >= total4) return;
    const int pad4 = NCH / 4;
    float4 v;
    if (idx < pad4) { v.x = 0.f; v.y = 0.f; v.z = 0.f; v.w = 0.f; }
    else v = ((const float4*)X)[idx - pad4];
    ushort4 o;
    o.x = f2bf(v.x); o.y = f2bf(v.y); o.z = f2bf(v.z); o.w = f2bf(v.w);
    ((ushort4*)Xbf)[idx] = o;
  }
}

// ---- 2) GEMM 64x128, BK=64, mfma_f32_16x16x32_bf16, swizzled LDS ----
// LDS seg (row, s) holds global k-seg s^(row&7)  (seg = 16B = 8 bf16)
// 1D grid 2048: bn=(id>>3)&3, bm=((id>>5)<<3)|(id&7) -> A-panel sharers same XCD.
__global__ __launch_bounds__(256) void gemm_kernel(
    const ushort* __restrict__ Xbf, const ushort* __restrict__ Bm,
    const float* __restrict__ bz, const float* __restrict__ bfb,
    ushort* __restrict__ zout, ushort* __restrict__ fout) {
  __shared__ __align__(16) char smem_raw[24576];
  ushort* sA = (ushort*)smem_raw;                 // 64 rows x 64 k   (8KB)
  ushort* sB = sA + 4096;                         // 128 cols x 64 k  (16KB)
  ushort* sT = (ushort*)smem_raw;                 // epilogue 64 x 136 (17.4KB)

  const int tid  = threadIdx.x;
  const int wave = tid >> 6;
  const int lane = tid & 63;
  const int quad = lane >> 4;
  const int lrow = lane & 15;
  const int wm = wave >> 1;          // 2x2 wave grid, each 32x64 output
  const int wn = wave & 1;
  const int id = blockIdx.x;         // 0..2047
  const int bn = (id >> 3) & 3;      // 0..3 (0,1=Z; 2,3=F)
  const int bm = ((id >> 5) << 3) | (id & 7);   // 0..511

  floatx4 acc[2][4];
#pragma unroll
  for (int i = 0; i < 2; ++i)
#pragma unroll
    for (int j = 0; j < 4; ++j)
      acc[i][j] = (floatx4){0.f, 0.f, 0.f, 0.f};

  // staging coords: A 2 segs/thread (512 segs), B 4 segs/thread (1024 segs)
  int rowA[2], gkoA[2], rowB[4], gkoB[4];
#pragma unroll
  for (int it = 0; it < 2; ++it) {
    int g = it * 256 + wave * 64 + lane;     // 0..511
    int row = g >> 3, s = g & 7;
    rowA[it] = row;                          // 0..63
    gkoA[it] = (s ^ (row & 7)) * 8;
  }
#pragma unroll
  for (int it = 0; it < 4; ++it) {
    int g = it * 256 + wave * 64 + lane;     // 0..1023
    int row = g >> 3, s = g & 7;
    rowB[it] = row;                          // 0..127
    gkoB[it] = (s ^ (row & 7)) * 8;
  }
  char* ldsA = smem_raw + wave * 1024 + (lane << 4);
  char* ldsB = smem_raw + 8192 + wave * 1024 + (lane << 4);

  const ushort* Arow = Xbf + (size_t)(bm * 64) * 256;
  const ushort* Brow = Bm + (size_t)(bn * 128) * 512;

  for (int k0 = 0; k0 < 512; k0 += 64) {
    __syncthreads();                 // prev iter ds_reads done
#pragma unroll
    for (int it = 0; it < 2; ++it) {
      const int kk = k0 + gkoA[it];
      const int cA = (kk < 256) ? kk : kk + 1792;     // tap1 lives +2048-256
      __builtin_amdgcn_global_load_lds(
          (const __attribute__((address_space(1))) void*)(Arow + (size_t)rowA[it] * 256 + cA),
          (__attribute__((address_space(3))) void*)(ldsA + it * 4096), 16, 0, 0);
    }
#pragma unroll
    for (int it = 0; it < 4; ++it) {
      const int kk = k0 + gkoB[it];
      __builtin_amdgcn_global_load_lds(
          (const __attribute__((address_space(1))) void*)(Brow + (size_t)rowB[it] * 512 + kk),
          (__attribute__((address_space(3))) void*)(ldsB + it * 4096), 16, 0, 0);
    }
    __syncthreads();

    bf16x8 af[2][2], bfr[4][2];
#pragma unroll
    for (int fi = 0; fi < 2; ++fi) {
      const int r = wm * 32 + fi * 16 + lrow;
#pragma unroll
      for (int ks = 0; ks < 2; ++ks) {
        const int s = (ks * 4 + quad) ^ (r & 7);
        af[fi][ks] = *(const bf16x8*)&sA[r * 64 + s * 8];
      }
    }
#pragma unroll
    for (int fj = 0; fj < 4; ++fj) {
      const int r = wn * 64 + fj * 16 + lrow;
#pragma unroll
      for (int ks = 0; ks < 2; ++ks) {
        const int s = (ks * 4 + quad) ^ (r & 7);
        bfr[fj][ks] = *(const bf16x8*)&sB[r * 64 + s * 8];
      }
    }
#pragma unroll
    for (int ks = 0; ks < 2; ++ks)
#pragma unroll
      for (int fi = 0; fi < 2; ++fi)
#pragma unroll
        for (int fj = 0; fj < 4; ++fj)
          acc[fi][fj] = __builtin_amdgcn_mfma_f32_16x16x32_bf16(af[fi][ks], bfr[fj][ks], acc[fi][fj], 0, 0, 0);
  }

  // epilogue: activation -> bf16 -> sT (64 x 136 padded) -> coalesced dwordx4
  const bool isZ = (bn < 2);
  ushort* gout = isZ ? zout : fout;
  const int ncol0 = (bn & 1) * 128;
  const float* bias = isZ ? bz : bfb;
  float bv[4];
#pragma unroll
  for (int fj = 0; fj < 4; ++fj)
    bv[fj] = bias[ncol0 + wn * 64 + fj * 16 + lrow];

  __syncthreads();                   // all ds_reads of sA/sB done (sT aliases)
#pragma unroll
  for (int fi = 0; fi < 2; ++fi)
#pragma unroll
    for (int fj = 0; fj < 4; ++fj)
#pragma unroll
      for (int r = 0; r < 4; ++r) {
        float v = acc[fi][fj][r] + bv[fj];
        float o = isZ ? (v * sigf(1.702f * v)) : sigf(v);
        sT[(wm * 32 + fi * 16 + quad * 4 + r) * 136 + wn * 64 + fj * 16 + lrow] = f2bf(o);
      }
  __syncthreads();
#pragma unroll
  for (int it = 0; it < 4; ++it) {
    int e = tid + it * 256;           // 1024 segs = 64 rows x 16 segs
    int row = e >> 4, seg = e & 15;
    uint4 v = *(uint4*)&sT[row * 136 + seg * 8];
    *(uint4*)(gout + (size_t)(bm * 64 + row) * 256 + ncol0 + seg * 8) = v;
  }
}

// ---- 3) per-chunk reduction, 2 channels/thread ----
__global__ void scanA_kernel(const ushort* __restrict__ z, const ushort* __restrict__ f,
                             float* __restrict__ Ac, float* __restrict__ Cc) {
  int t = blockIdx.x * blockDim.x + threadIdx.x;   // 0..131071
  int ch2 = t & 1023;
  int j = t >> 10;                                  // 0..127
  const size_t base = (size_t)j * CHUNK * NCH + 2 * ch2;
  const ushort* zp = z + base;
  const ushort* fp = f + base;
  float A0 = 1.0f, C0 = 0.0f, A1 = 1.0f, C1 = 0.0f;
#pragma unroll
  for (int i = 0; i < CHUNK; ++i) {
    ushort2 fv = *(const ushort2*)(fp + (size_t)i * NCH);
    ushort2 zv = *(const ushort2*)(zp + (size_t)i * NCH);
    float f0 = bf2f(fv.x), f1 = bf2f(fv.y);
    float a0 = 1.0f - f0, a1 = 1.0f - f1;
    C0 = fmaf(a0, C0, f0 * bf2f(zv.x)); A0 *= a0;
    C1 = fmaf(a1, C1, f1 * bf2f(zv.y)); A1 *= a1;
  }
  float2 Av = {A0, A1}, Cv = {C0, C1};
  *(float2*)(Ac + (size_t)j * NCH + 2 * ch2) = Av;
  *(float2*)(Cc + (size_t)j * NCH + 2 * ch2) = Cv;
}

// ---- 4) replay within chunk + inline cross-chunk lookback, 2 ch/thread ----
__global__ void scanC_kernel(const float* __restrict__ hidden,
                             const ushort* __restrict__ z, const ushort* __restrict__ f,
                             const float* __restrict__ Ac, const float* __restrict__ Cc,
                             float* __restrict__ out) {
  int t = blockIdx.x * blockDim.x + threadIdx.x;   // 0..131071
  int ch2 = t & 1023;
  int j = t >> 10;                                  // chunk 0..127

  // inline lookback: fold chunks 0..j-1 (Ac/Cc are L2-resident, 2MB total).
  // (a,c): h_start_j = a*h0 + c. Loads are chain-independent -> pipeline.
  float a0r = 1.f, c0r = 0.f, a1r = 1.f, c1r = 0.f;
  const float* Ap = Ac + 2 * ch2;
  const float* Cp = Cc + 2 * ch2;
#pragma unroll 4
  for (int jj = 0; jj < j; ++jj) {
    float2 Av = *(const float2*)(Ap + (size_t)jj * NCH);
    float2 Cv = *(const float2*)(Cp + (size_t)jj * NCH);
    c0r = fmaf(Av.x, c0r, Cv.x); a0r *= Av.x;
    c1r = fmaf(Av.y, c1r, Cv.y); a1r *= Av.y;
  }
  float2 hv = *(const float2*)(hidden + 2 * ch2);
  float h0 = fmaf(a0r, hv.x, c0r);
  float h1 = fmaf(a1r, hv.y, c1r);

  const size_t base = (size_t)j * CHUNK * NCH + 2 * ch2;
  const ushort* zp = z + base;
  const ushort* fp = f + base;
  float* op = out + base;
#pragma unroll
  for (int i = 0; i < CHUNK; ++i) {
    ushort2 fv = *(const ushort2*)(fp + (size_t)i * NCH);
    ushort2 zv = *(const ushort2*)(zp + (size_t)i * NCH);
    float f0 = bf2f(fv.x), f1 = bf2f(fv.y);
    h0 = fmaf(f0, bf2f(zv.x) - h0, h0);
    h1 = fmaf(f1, bf2f(zv.y) - h1, h1);
    float2 o = {h0, h1};
    *(float2*)(op + (size_t)i * NCH) = o;
  }
  if (j == NCHUNK - 1) {
    float2 o = {h0, h1};
    *(float2*)(out + (size_t)SEQn * NCH + 2 * ch2) = o;   // h_last row
  }
}

extern "C" void kernel_launch(void* const* d_in, const int* in_sizes, int n_in,
                              void* d_out, int out_size, void* d_ws, size_t ws_size,
                              hipStream_t stream) {
  const float* X      = (const float*)d_in[0];
  const float* hidden = (const float*)d_in[1];
  const float* Wz     = (const float*)d_in[2];
  const float* bz     = (const float*)d_in[3];
  const float* Wf     = (const float*)d_in[4];
  const float* bfb    = (const float*)d_in[5];
  float* out = (float*)d_out;

  char* ws = (char*)d_ws;
  ushort* zbf = (ushort*)ws;                       // 16,777,216 B
  ushort* fbf = (ushort*)(ws + 16777216);          // 16,777,216 B
  ushort* Xbf = (ushort*)(ws + 33554432);          // 16,781,312 B (dead after gemm)
  ushort* Bm  = (ushort*)(ws + 50335744);          //    524,288 B
  // aliased over Xbf (used only after gemm completes):
  float* Ac = (float*)(ws + 33554432);
  float* Cc = (float*)(ws + 34603008);

  pack_kernel<<<9218, 256, 0, stream>>>(X, Wz, Wf, Xbf, Bm);
  gemm_kernel<<<2048, 256, 0, stream>>>(Xbf, Bm, bz, bfb, zbf, fbf);
  scanA_kernel<<<512, 256, 0, stream>>>(zbf, fbf, Ac, Cc);
  scanC_kernel<<<512, 256, 0, stream>>>(hidden, zbf, fbf, Ac, Cc, out);
}

// Round 15
// 141.774 us; speedup vs baseline: 1.0148x; 1.0069x over previous
//
#include <hip/hip_runtime.h>

// QRNN: SEQ=4096, BATCH=8, CIN=256, HID=256, K=2 (lookback=1)
// R15: R9 (verified best, 138.0us) + TRUE counted-vmcnt pipeline (T3/T4):
//      dbuf 2x24KB; per iter: STAGE(next 6 loads) -> s_waitcnt vmcnt(6)
//      (prev tile landed, NEW 6 stay in flight through MFMA) -> raw s_barrier
//      -> compute -> raw s_barrier. R6/R11/R13 all used __syncthreads = vmcnt(0)
//      drain each step (never actually overlapped; guide m218: counted IS the
//      gain). sched_barrier(0) fences around barriers per rule #18.
//
// ws: zbf 16MB | fbf 16MB | Xbf 16MB (dead after gemm; Ac/Cc/Hs aliased) | Bm 0.5MB

#define SEQn 4096
#define NCH 2048          // BATCH*HID channels
#define CHUNK 32
#define NCHUNK 128

typedef __attribute__((ext_vector_type(8))) short bf16x8;
typedef __attribute__((ext_vector_type(4))) float floatx4;

__device__ __forceinline__ unsigned short f2bf(float x) {
  unsigned int u = __float_as_uint(x);
  u += 0x7fffu + ((u >> 16) & 1u);     // RNE
  return (unsigned short)(u >> 16);
}
__device__ __forceinline__ float bf2f(ushort u) {
  return __uint_as_float((unsigned int)u << 16);
}
__device__ __forceinline__ float sigf(float x) {
  return __builtin_amdgcn_rcpf(1.0f + __expf(-x));
}

// ---- 1) merged pack: blocks [0,1024) pack W, blocks [1024,9218) pack X ----
__global__ void pack_kernel(const float* __restrict__ X,
                            const float* __restrict__ Wz, const float* __restrict__ Wf,
                            ushort* __restrict__ Xbf, ushort* __restrict__ Bm) {
  if (blockIdx.x < 1024) {
    int idx = blockIdx.x * 256 + threadIdx.x;        // 0..262143
    int n = idx >> 9, kin = idx & 511;
    const float* W = (n < 256) ? Wz : Wf;
    int h = n & 255, c = kin & 255, tap = kin >> 8;  // kin<256: tap0 (X[s-1])
    Bm[idx] = f2bf(W[h * 512 + c * 2 + tap]);
  } else {
    int idx = (blockIdx.x - 1024) * 256 + threadIdx.x;
    const int total4 = ((SEQn + 1) * NCH) / 4;       // 2,097,664
    if (idx >= total4) return;
    const int pad4 = NCH / 4;
    float4 v;
    if (idx < pad4) { v.x = 0.f; v.y = 0.f; v.z = 0.f; v.w = 0.f; }
    else v = ((const float4*)X)[idx - pad4];
    ushort4 o;
    o.x = f2bf(v.x); o.y = f2bf(v.y); o.z = f2bf(v.z); o.w = f2bf(v.w);
    ((ushort4*)Xbf)[idx] = o;
  }
}

// ---- 2) GEMM 64x128, BK=64, dbuf + counted vmcnt, swizzled LDS ----
// LDS seg (row, s) holds global k-seg s^(row&7)  (seg = 16B = 8 bf16)
// 1D grid 2048: bn=(id>>3)&3, bm=((id>>5)<<3)|(id&7) -> A-panel sharers same XCD.
__global__ __launch_bounds__(256) void gemm_kernel(
    const ushort* __restrict__ Xbf, const ushort* __restrict__ Bm,
    const float* __restrict__ bz, const float* __restrict__ bfb,
    ushort* __restrict__ zout, ushort* __restrict__ fout) {
  __shared__ __align__(16) char smem_raw[49152];
  // buffer c at c*24576: sA 64x64 (8KB) then sB 128x64 (16KB)
  ushort* sT = (ushort*)smem_raw;                 // epilogue 64 x 136 (17.4KB)

  const int tid  = threadIdx.x;
  const int wave = tid >> 6;
  const int lane = tid & 63;
  const int quad = lane >> 4;
  const int lrow = lane & 15;
  const int wm = wave >> 1;          // 2x2 wave grid, each 32x64 output
  const int wn = wave & 1;
  const int id = blockIdx.x;         // 0..2047
  const int bn = (id >> 3) & 3;      // 0..3 (0,1=Z; 2,3=F)
  const int bm = ((id >> 5) << 3) | (id & 7);   // 0..511

  floatx4 acc[2][4];
#pragma unroll
  for (int i = 0; i < 2; ++i)
#pragma unroll
    for (int j = 0; j < 4; ++j)
      acc[i][j] = (floatx4){0.f, 0.f, 0.f, 0.f};

  // staging coords: A 2 segs/thread (512 segs), B 4 segs/thread (1024 segs)
  int rowA[2], gkoA[2], rowB[4], gkoB[4];
#pragma unroll
  for (int it = 0; it < 2; ++it) {
    int g = it * 256 + wave * 64 + lane;     // 0..511
    int row = g >> 3, s = g & 7;
    rowA[it] = row;                          // 0..63
    gkoA[it] = (s ^ (row & 7)) * 8;
  }
#pragma unroll
  for (int it = 0; it < 4; ++it) {
    int g = it * 256 + wave * 64 + lane;     // 0..1023
    int row = g >> 3, s = g & 7;
    rowB[it] = row;                          // 0..127
    gkoB[it] = (s ^ (row & 7)) * 8;
  }

  const ushort* Arow = Xbf + (size_t)(bm * 64) * 256;
  const ushort* Brow = Bm + (size_t)(bn * 128) * 512;

#define STAGE(curb, k0)                                                          \
  {                                                                              \
    char* lA = smem_raw + (curb) * 24576 + wave * 1024 + (lane << 4);            \
    char* lB = lA + 8192;                                                        \
    _Pragma("unroll")                                                            \
    for (int it = 0; it < 2; ++it) {                                             \
      const int kk = (k0) + gkoA[it];                                            \
      const int cA = (kk < 256) ? kk : kk + 1792;  /* tap1 lives +2048-256 */    \
      __builtin_amdgcn_global_load_lds(                                          \
          (const __attribute__((address_space(1))) void*)(Arow + (size_t)rowA[it] * 256 + cA), \
          (__attribute__((address_space(3))) void*)(lA + it * 4096), 16, 0, 0);  \
    }                                                                            \
    _Pragma("unroll")                                                            \
    for (int it = 0; it < 4; ++it) {                                             \
      const int kk = (k0) + gkoB[it];                                            \
      __builtin_amdgcn_global_load_lds(                                          \
          (const __attribute__((address_space(1))) void*)(Brow + (size_t)rowB[it] * 512 + kk), \
          (__attribute__((address_space(3))) void*)(lB + it * 4096), 16, 0, 0);  \
    }                                                                            \
  }

  STAGE(0, 0);                       // prologue: tile 0 in flight

#pragma unroll
  for (int t = 0; t < 8; ++t) {
    const int cur = t & 1;
    if (t < 7) {
      STAGE(cur ^ 1, (t + 1) * 64);  // issue next tile: stays in flight through MFMA
      asm volatile("s_waitcnt vmcnt(6)" ::: "memory");   // only tile t's 6 loads landed
    } else {
      asm volatile("s_waitcnt vmcnt(0)" ::: "memory");   // last tile: drain
    }
    __builtin_amdgcn_sched_barrier(0);
    __builtin_amdgcn_s_barrier();    // all waves: tile t complete in LDS
    __builtin_amdgcn_sched_barrier(0);

    const ushort* sA = (const ushort*)(smem_raw + cur * 24576);
    const ushort* sB = sA + 4096;    // +8192 bytes

    bf16x8 af[2][2], bfr[4][2];
#pragma unroll
    for (int fi = 0; fi < 2; ++fi) {
      const int r = wm * 32 + fi * 16 + lrow;
#pragma unroll
      for (int ks = 0; ks < 2; ++ks) {
        const int s = (ks * 4 + quad) ^ (r & 7);
        af[fi][ks] = *(const bf16x8*)&sA[r * 64 + s * 8];
      }
    }
#pragma unroll
    for (int fj = 0; fj < 4; ++fj) {
      const int r = wn * 64 + fj * 16 + lrow;
#pragma unroll
      for (int ks = 0; ks < 2; ++ks) {
        const int s = (ks * 4 + quad) ^ (r & 7);
        bfr[fj][ks] = *(const bf16x8*)&sB[r * 64 + s * 8];
      }
    }
#pragma unroll
    for (int ks = 0; ks < 2; ++ks)
#pragma unroll
      for (int fi = 0; fi < 2; ++fi)
#pragma unroll
        for (int fj = 0; fj < 4; ++fj)
          acc[fi][fj] = __builtin_amdgcn_mfma_f32_16x16x32_bf16(af[fi][ks], bfr[fj][ks], acc[fi][fj], 0, 0, 0);

    __builtin_amdgcn_sched_barrier(0);
    __builtin_amdgcn_s_barrier();    // all waves done reading buf cur (next STAGE overwrites it)
    __builtin_amdgcn_sched_barrier(0);
  }
#undef STAGE

  // epilogue: activation -> bf16 -> sT (64 x 136 padded) -> coalesced dwordx4
  const bool isZ = (bn < 2);
  ushort* gout = isZ ? zout : fout;
  const int ncol0 = (bn & 1) * 128;
  const float* bias = isZ ? bz : bfb;
  float bv[4];
#pragma unroll
  for (int fj = 0; fj < 4; ++fj)
    bv[fj] = bias[ncol0 + wn * 64 + fj * 16 + lrow];

#pragma unroll
  for (int fi = 0; fi < 2; ++fi)
#pragma unroll
    for (int fj = 0; fj < 4; ++fj)
#pragma unroll
      for (int r = 0; r < 4; ++r) {
        float v = acc[fi][fj][r] + bv[fj];
        float o = isZ ? (v * sigf(1.702f * v)) : sigf(v);
        sT[(wm * 32 + fi * 16 + quad * 4 + r) * 136 + wn * 64 + fj * 16 + lrow] = f2bf(o);
      }
  __syncthreads();
#pragma unroll
  for (int it = 0; it < 4; ++it) {
    int e = tid + it * 256;           // 1024 segs = 64 rows x 16 segs
    int row = e >> 4, seg = e & 15;
    uint4 v = *(uint4*)&sT[row * 136 + seg * 8];
    *(uint4*)(gout + (size_t)(bm * 64 + row) * 256 + ncol0 + seg * 8) = v;
  }
}

// ---- 3) per-chunk reduction, 2 channels/thread ----
__global__ void scanA_kernel(const ushort* __restrict__ z, const ushort* __restrict__ f,
                             float* __restrict__ Ac, float* __restrict__ Cc) {
  int t = blockIdx.x * blockDim.x + threadIdx.x;   // 0..131071
  int ch2 = t & 1023;
  int j = t >> 10;                                  // 0..127
  const size_t base = (size_t)j * CHUNK * NCH + 2 * ch2;
  const ushort* zp = z + base;
  const ushort* fp = f + base;
  float A0 = 1.0f, C0 = 0.0f, A1 = 1.0f, C1 = 0.0f;
#pragma unroll
  for (int i = 0; i < CHUNK; ++i) {
    ushort2 fv = *(const ushort2*)(fp + (size_t)i * NCH);
    ushort2 zv = *(const ushort2*)(zp + (size_t)i * NCH);
    float f0 = bf2f(fv.x), f1 = bf2f(fv.y);
    float a0 = 1.0f - f0, a1 = 1.0f - f1;
    C0 = fmaf(a0, C0, f0 * bf2f(zv.x)); A0 *= a0;
    C1 = fmaf(a1, C1, f1 * bf2f(zv.y)); A1 *= a1;
  }
  float2 Av = {A0, A1}, Cv = {C0, C1};
  *(float2*)(Ac + (size_t)j * NCH + 2 * ch2) = Av;
  *(float2*)(Cc + (size_t)j * NCH + 2 * ch2) = Cv;
}

// ---- 4) cross-chunk scan: one wave per channel, shfl Hillis-Steele ----
__global__ void scanB_kernel(const float* __restrict__ hidden,
                             const float* __restrict__ Ac, const float* __restrict__ Cc,
                             float* __restrict__ Hs) {
  const int lane = threadIdx.x & 63;
  const int ch = blockIdx.x * 4 + (threadIdx.x >> 6);   // 512 blocks x 4 waves
  const int j0 = 2 * lane, j1 = 2 * lane + 1;
  float a0 = Ac[j0 * NCH + ch], c0 = Cc[j0 * NCH + ch];
  float a1 = Ac[j1 * NCH + ch], c1 = Cc[j1 * NCH + ch];
  float a = a0 * a1;
  float c = fmaf(a1, c0, c1);
#pragma unroll
  for (int d = 1; d < 64; d <<= 1) {
    float pa = __shfl_up(a, d, 64);
    float pc = __shfl_up(c, d, 64);
    if (lane >= d) { c = fmaf(a, pc, c); a *= pa; }
  }
  float xa = __shfl_up(a, 1, 64), xc = __shfl_up(c, 1, 64);
  if (lane == 0) { xa = 1.0f; xc = 0.0f; }
  float h0 = hidden[ch];
  float hs0 = fmaf(xa, h0, xc);
  Hs[j0 * NCH + ch] = hs0;
  Hs[j1 * NCH + ch] = fmaf(a0, hs0, c0);
}

// ---- 5) replay within chunk, 2 channels/thread, fp32 out ----
__global__ void scanC_kernel(const ushort* __restrict__ z, const ushort* __restrict__ f,
                             const float* __restrict__ Hs, float* __restrict__ out) {
  int t = blockIdx.x * blockDim.x + threadIdx.x;   // 0..131071
  int ch2 = t & 1023;
  int j = t >> 10;
  float2 hv = *(const float2*)(Hs + (size_t)j * NCH + 2 * ch2);
  float h0 = hv.x, h1 = hv.y;
  const size_t base = (size_t)j * CHUNK * NCH + 2 * ch2;
  const ushort* zp = z + base;
  const ushort* fp = f + base;
  float* op = out + base;
#pragma unroll
  for (int i = 0; i < CHUNK; ++i) {
    ushort2 fv = *(const ushort2*)(fp + (size_t)i * NCH);
    ushort2 zv = *(const ushort2*)(zp + (size_t)i * NCH);
    float f0 = bf2f(fv.x), f1 = bf2f(fv.y);
    h0 = fmaf(f0, bf2f(zv.x) - h0, h0);
    h1 = fmaf(f1, bf2f(zv.y) - h1, h1);
    float2 o = {h0, h1};
    *(float2*)(op + (size_t)i * NCH) = o;
  }
  if (j == NCHUNK - 1) {
    float2 o = {h0, h1};
    *(float2*)(out + (size_t)SEQn * NCH + 2 * ch2) = o;   // h_last row
  }
}

extern "C" void kernel_launch(void* const* d_in, const int* in_sizes, int n_in,
                              void* d_out, int out_size, void* d_ws, size_t ws_size,
                              hipStream_t stream) {
  const float* X      = (const float*)d_in[0];
  const float* hidden = (const float*)d_in[1];
  const float* Wz     = (const float*)d_in[2];
  const float* bz     = (const float*)d_in[3];
  const float* Wf     = (const float*)d_in[4];
  const float* bfb    = (const float*)d_in[5];
  float* out = (float*)d_out;

  char* ws = (char*)d_ws;
  ushort* zbf = (ushort*)ws;                       // 16,777,216 B
  ushort* fbf = (ushort*)(ws + 16777216);          // 16,777,216 B
  ushort* Xbf = (ushort*)(ws + 33554432);          // 16,781,312 B (dead after gemm)
  ushort* Bm  = (ushort*)(ws + 50335744);          //    524,288 B
  // aliased over Xbf (used only after gemm completes):
  float* Ac = (float*)(ws + 33554432);
  float* Cc = (float*)(ws + 34603008);
  float* Hs = (float*)(ws + 35651584);

  pack_kernel<<<9218, 256, 0, stream>>>(X, Wz, Wf, Xbf, Bm);
  gemm_kernel<<<2048, 256, 0, stream>>>(Xbf, Bm, bz, bfb, zbf, fbf);
  scanA_kernel<<<512, 256, 0, stream>>>(zbf, fbf, Ac, Cc);
  scanB_kernel<<<512, 256, 0, stream>>>(hidden, Ac, Cc, Hs);
  scanC_kernel<<<512, 256, 0, stream>>>(zbf, fbf, Hs, out);
}

// Round 16
// 140.154 us; speedup vs baseline: 1.0265x; 1.0116x over previous
//
#include <hip/hip_runtime.h>

// QRNN: SEQ=4096, BATCH=8, CIN=256, HID=256, K=2 (lookback=1)
// R9-FINAL (best verified, 137.96us): merged pack; gemm 64x128 BK=64
// single-buffer 24KB LDS (6 blocks/CU), XCD-aware 1D decode (A-panel sharers
// same XCD); scanA/B/C 3-kernel log-depth scan.
// Session ledger: wins = tile-shrink occupancy (R7), XCD decode (R9).
// Null/regressed = grid-sync fusion x2, epilogue-fused partials, sync A-fold,
// LDS dbuf x3, 32-wave max-TLP, BK=128, scanB-fold, counted-vmcnt (R15:
// FETCH 27.5->11.4GB but dur unchanged -> fetch was never the limiter; gemm
// is ~1.7x its LDS-BW floor, served by cross-block TLP, not pipelining).
//
// ws: zbf 16MB | fbf 16MB | Xbf 16MB (dead after gemm; Ac/Cc/Hs aliased) | Bm 0.5MB

#define SEQn 4096
#define NCH 2048          // BATCH*HID channels
#define CHUNK 32
#define NCHUNK 128

typedef __attribute__((ext_vector_type(8))) short bf16x8;
typedef __attribute__((ext_vector_type(4))) float floatx4;

__device__ __forceinline__ unsigned short f2bf(float x) {
  unsigned int u = __float_as_uint(x);
  u += 0x7fffu + ((u >> 16) & 1u);     // RNE
  return (unsigned short)(u >> 16);
}
__device__ __forceinline__ float bf2f(ushort u) {
  return __uint_as_float((unsigned int)u << 16);
}
__device__ __forceinline__ float sigf(float x) {
  return __builtin_amdgcn_rcpf(1.0f + __expf(-x));
}

// ---- 1) merged pack: blocks [0,1024) pack W, blocks [1024,9218) pack X ----
__global__ void pack_kernel(const float* __restrict__ X,
                            const float* __restrict__ Wz, const float* __restrict__ Wf,
                            ushort* __restrict__ Xbf, ushort* __restrict__ Bm) {
  if (blockIdx.x < 1024) {
    int idx = blockIdx.x * 256 + threadIdx.x;        // 0..262143
    int n = idx >> 9, kin = idx & 511;
    const float* W = (n < 256) ? Wz : Wf;
    int h = n & 255, c = kin & 255, tap = kin >> 8;  // kin<256: tap0 (X[s-1])
    Bm[idx] = f2bf(W[h * 512 + c * 2 + tap]);
  } else {
    int idx = (blockIdx.x - 1024) * 256 + threadIdx.x;
    const int total4 = ((SEQn + 1) * NCH) / 4;       // 2,097,664
    if (idx >= total4) return;
    const int pad4 = NCH / 4;
    float4 v;
    if (idx < pad4) { v.x = 0.f; v.y = 0.f; v.z = 0.f; v.w = 0.f; }
    else v = ((const float4*)X)[idx - pad4];
    ushort4 o;
    o.x = f2bf(v.x); o.y = f2bf(v.y); o.z = f2bf(v.z); o.w = f2bf(v.w);
    ((ushort4*)Xbf)[idx] = o;
  }
}

// ---- 2) GEMM 64x128, BK=64, mfma_f32_16x16x32_bf16, swizzled LDS ----
// LDS seg (row, s) holds global k-seg s^(row&7)  (seg = 16B = 8 bf16)
// 1D grid 2048: xcd=id&7, bn=(id>>3)&3, bm=((id>>5)<<3)|(id&7)  -> A-panel sharers
// (same bm, 4 bn) have same id%8 => same XCD L2, adjacent dispatch time.
__global__ __launch_bounds__(256) void gemm_kernel(
    const ushort* __restrict__ Xbf, const ushort* __restrict__ Bm,
    const float* __restrict__ bz, const float* __restrict__ bfb,
    ushort* __restrict__ zout, ushort* __restrict__ fout) {
  __shared__ __align__(16) char smem_raw[24576];
  ushort* sA = (ushort*)smem_raw;                 // 64 rows x 64 k   (8KB)
  ushort* sB = sA + 4096;                         // 128 cols x 64 k  (16KB)
  ushort* sT = (ushort*)smem_raw;                 // epilogue 64 x 136 (17.4KB)

  const int tid  = threadIdx.x;
  const int wave = tid >> 6;
  const int lane = tid & 63;
  const int quad = lane >> 4;
  const int lrow = lane & 15;
  const int wm = wave >> 1;          // 2x2 wave grid, each 32x64 output
  const int wn = wave & 1;
  const int id = blockIdx.x;         // 0..2047
  const int bn = (id >> 3) & 3;      // 0..3 (0,1=Z; 2,3=F)
  const int bm = ((id >> 5) << 3) | (id & 7);   // 0..511

  floatx4 acc[2][4];
#pragma unroll
  for (int i = 0; i < 2; ++i)
#pragma unroll
    for (int j = 0; j < 4; ++j)
      acc[i][j] = (floatx4){0.f, 0.f, 0.f, 0.f};

  // staging coords: A 2 segs/thread (512 segs), B 4 segs/thread (1024 segs)
  int rowA[2], gkoA[2], rowB[4], gkoB[4];
#pragma unroll
  for (int it = 0; it < 2; ++it) {
    int g = it * 256 + wave * 64 + lane;     // 0..511
    int row = g >> 3, s = g & 7;
    rowA[it] = row;                          // 0..63
    gkoA[it] = (s ^ (row & 7)) * 8;
  }
#pragma unroll
  for (int it = 0; it < 4; ++it) {
    int g = it * 256 + wave * 64 + lane;     // 0..1023
    int row = g >> 3, s = g & 7;
    rowB[it] = row;                          // 0..127
    gkoB[it] = (s ^ (row & 7)) * 8;
  }
  char* ldsA = smem_raw + wave * 1024 + (lane << 4);
  char* ldsB = smem_raw + 8192 + wave * 1024 + (lane << 4);

  const ushort* Arow = Xbf + (size_t)(bm * 64) * 256;
  const ushort* Brow = Bm + (size_t)(bn * 128) * 512;

  for (int k0 = 0; k0 < 512; k0 += 64) {
    __syncthreads();                 // prev iter ds_reads done
#pragma unroll
    for (int it = 0; it < 2; ++it) {
      const int kk = k0 + gkoA[it];
      const int cA = (kk < 256) ? kk : kk + 1792;     // tap1 lives +2048-256
      __builtin_amdgcn_global_load_lds(
          (const __attribute__((address_space(1))) void*)(Arow + (size_t)rowA[it] * 256 + cA),
          (__attribute__((address_space(3))) void*)(ldsA + it * 4096), 16, 0, 0);
    }
#pragma unroll
    for (int it = 0; it < 4; ++it) {
      const int kk = k0 + gkoB[it];
      __builtin_amdgcn_global_load_lds(
          (const __attribute__((address_space(1))) void*)(Brow + (size_t)rowB[it] * 512 + kk),
          (__attribute__((address_space(3))) void*)(ldsB + it * 4096), 16, 0, 0);
    }
    __syncthreads();

    bf16x8 af[2][2], bfr[4][2];
#pragma unroll
    for (int fi = 0; fi < 2; ++fi) {
      const int r = wm * 32 + fi * 16 + lrow;
#pragma unroll
      for (int ks = 0; ks < 2; ++ks) {
        const int s = (ks * 4 + quad) ^ (r & 7);
        af[fi][ks] = *(const bf16x8*)&sA[r * 64 + s * 8];
      }
    }
#pragma unroll
    for (int fj = 0; fj < 4; ++fj) {
      const int r = wn * 64 + fj * 16 + lrow;
#pragma unroll
      for (int ks = 0; ks < 2; ++ks) {
        const int s = (ks * 4 + quad) ^ (r & 7);
        bfr[fj][ks] = *(const bf16x8*)&sB[r * 64 + s * 8];
      }
    }
#pragma unroll
    for (int ks = 0; ks < 2; ++ks)
#pragma unroll
      for (int fi = 0; fi < 2; ++fi)
#pragma unroll
        for (int fj = 0; fj < 4; ++fj)
          acc[fi][fj] = __builtin_amdgcn_mfma_f32_16x16x32_bf16(af[fi][ks], bfr[fj][ks], acc[fi][fj], 0, 0, 0);
  }

  // epilogue: activation -> bf16 -> sT (64 x 136 padded) -> coalesced dwordx4
  const bool isZ = (bn < 2);
  ushort* gout = isZ ? zout : fout;
  const int ncol0 = (bn & 1) * 128;
  const float* bias = isZ ? bz : bfb;
  float bv[4];
#pragma unroll
  for (int fj = 0; fj < 4; ++fj)
    bv[fj] = bias[ncol0 + wn * 64 + fj * 16 + lrow];

  __syncthreads();                   // all ds_reads of sA/sB done (sT aliases)
#pragma unroll
  for (int fi = 0; fi < 2; ++fi)
#pragma unroll
    for (int fj = 0; fj < 4; ++fj)
#pragma unroll
      for (int r = 0; r < 4; ++r) {
        float v = acc[fi][fj][r] + bv[fj];
        float o = isZ ? (v * sigf(1.702f * v)) : sigf(v);
        sT[(wm * 32 + fi * 16 + quad * 4 + r) * 136 + wn * 64 + fj * 16 + lrow] = f2bf(o);
      }
  __syncthreads();
#pragma unroll
  for (int it = 0; it < 4; ++it) {
    int e = tid + it * 256;           // 1024 segs = 64 rows x 16 segs
    int row = e >> 4, seg = e & 15;
    uint4 v = *(uint4*)&sT[row * 136 + seg * 8];
    *(uint4*)(gout + (size_t)(bm * 64 + row) * 256 + ncol0 + seg * 8) = v;
  }
}

// ---- 3) per-chunk reduction, 2 channels/thread ----
__global__ void scanA_kernel(const ushort* __restrict__ z, const ushort* __restrict__ f,
                             float* __restrict__ Ac, float* __restrict__ Cc) {
  int t = blockIdx.x * blockDim.x + threadIdx.x;   // 0..131071
  int ch2 = t & 1023;
  int j = t >> 10;                                  // 0..127
  const size_t base = (size_t)j * CHUNK * NCH + 2 * ch2;
  const ushort* zp = z + base;
  const ushort* fp = f + base;
  float A0 = 1.0f, C0 = 0.0f, A1 = 1.0f, C1 = 0.0f;
#pragma unroll
  for (int i = 0; i < CHUNK; ++i) {
    ushort2 fv = *(const ushort2*)(fp + (size_t)i * NCH);
    ushort2 zv = *(const ushort2*)(zp + (size_t)i * NCH);
    float f0 = bf2f(fv.x), f1 = bf2f(fv.y);
    float a0 = 1.0f - f0, a1 = 1.0f - f1;
    C0 = fmaf(a0, C0, f0 * bf2f(zv.x)); A0 *= a0;
    C1 = fmaf(a1, C1, f1 * bf2f(zv.y)); A1 *= a1;
  }
  float2 Av = {A0, A1}, Cv = {C0, C1};
  *(float2*)(Ac + (size_t)j * NCH + 2 * ch2) = Av;
  *(float2*)(Cc + (size_t)j * NCH + 2 * ch2) = Cv;
}

// ---- 4) cross-chunk scan: one wave per channel, shfl Hillis-Steele ----
__global__ void scanB_kernel(const float* __restrict__ hidden,
                             const float* __restrict__ Ac, const float* __restrict__ Cc,
                             float* __restrict__ Hs) {
  const int lane = threadIdx.x & 63;
  const int ch = blockIdx.x * 4 + (threadIdx.x >> 6);   // 512 blocks x 4 waves
  const int j0 = 2 * lane, j1 = 2 * lane + 1;
  float a0 = Ac[j0 * NCH + ch], c0 = Cc[j0 * NCH + ch];
  float a1 = Ac[j1 * NCH + ch], c1 = Cc[j1 * NCH + ch];
  float a = a0 * a1;
  float c = fmaf(a1, c0, c1);
#pragma unroll
  for (int d = 1; d < 64; d <<= 1) {
    float pa = __shfl_up(a, d, 64);
    float pc = __shfl_up(c, d, 64);
    if (lane >= d) { c = fmaf(a, pc, c); a *= pa; }
  }
  float xa = __shfl_up(a, 1, 64), xc = __shfl_up(c, 1, 64);
  if (lane == 0) { xa = 1.0f; xc = 0.0f; }
  float h0 = hidden[ch];
  float hs0 = fmaf(xa, h0, xc);
  Hs[j0 * NCH + ch] = hs0;
  Hs[j1 * NCH + ch] = fmaf(a0, hs0, c0);
}

// ---- 5) replay within chunk, 2 channels/thread, fp32 out ----
__global__ void scanC_kernel(const ushort* __restrict__ z, const ushort* __restrict__ f,
                             const float* __restrict__ Hs, float* __restrict__ out) {
  int t = blockIdx.x * blockDim.x + threadIdx.x;   // 0..131071
  int ch2 = t & 1023;
  int j = t >> 10;
  float2 hv = *(const float2*)(Hs + (size_t)j * NCH + 2 * ch2);
  float h0 = hv.x, h1 = hv.y;
  const size_t base = (size_t)j * CHUNK * NCH + 2 * ch2;
  const ushort* zp = z + base;
  const ushort* fp = f + base;
  float* op = out + base;
#pragma unroll
  for (int i = 0; i < CHUNK; ++i) {
    ushort2 fv = *(const ushort2*)(fp + (size_t)i * NCH);
    ushort2 zv = *(const ushort2*)(zp + (size_t)i * NCH);
    float f0 = bf2f(fv.x), f1 = bf2f(fv.y);
    h0 = fmaf(f0, bf2f(zv.x) - h0, h0);
    h1 = fmaf(f1, bf2f(zv.y) - h1, h1);
    float2 o = {h0, h1};
    *(float2*)(op + (size_t)i * NCH) = o;
  }
  if (j == NCHUNK - 1) {
    float2 o = {h0, h1};
    *(float2*)(out + (size_t)SEQn * NCH + 2 * ch2) = o;   // h_last row
  }
}

extern "C" void kernel_launch(void* const* d_in, const int* in_sizes, int n_in,
                              void* d_out, int out_size, void* d_ws, size_t ws_size,
                              hipStream_t stream) {
  const float* X      = (const float*)d_in[0];
  const float* hidden = (const float*)d_in[1];
  const float* Wz     = (const float*)d_in[2];
  const float* bz     = (const float*)d_in[3];
  const float* Wf     = (const float*)d_in[4];
  const float* bfb    = (const float*)d_in[5];
  float* out = (float*)d_out;

  char* ws = (char*)d_ws;
  ushort* zbf = (ushort*)ws;                       // 16,777,216 B
  ushort* fbf = (ushort*)(ws + 16777216);          // 16,777,216 B
  ushort* Xbf = (ushort*)(ws + 33554432);          // 16,781,312 B (dead after gemm)
  ushort* Bm  = (ushort*)(ws + 50335744);          //    524,288 B
  // aliased over Xbf (used only after gemm completes):
  float* Ac = (float*)(ws + 33554432);
  float* Cc = (float*)(ws + 34603008);
  float* Hs = (float*)(ws + 35651584);

  pack_kernel<<<9218, 256, 0, stream>>>(X, Wz, Wf, Xbf, Bm);
  gemm_kernel<<<2048, 256, 0, stream>>>(Xbf, Bm, bz, bfb, zbf, fbf);
  scanA_kernel<<<512, 256, 0, stream>>>(zbf, fbf, Ac, Cc);
  scanB_kernel<<<512, 256, 0, stream>>>(hidden, Ac, Cc, Hs);
  scanC_kernel<<<512, 256, 0, stream>>>(zbf, fbf, Hs, out);
}